// Round 3
// baseline (503.980 us; speedup 1.0000x reference)
//
#include <hip/hip_runtime.h>
#include <hip/hip_bf16.h>

#define EMB 1024
#define CTX 32
#define NEXP 16
#define H1 2048
#define H2 512
#define NBIG 16384  // F_IN*R == R*F_OUT

typedef __attribute__((ext_vector_type(8))) short short8;
typedef __attribute__((ext_vector_type(4))) float floatx4;

__device__ inline unsigned short bf_bits(float x) {
  unsigned u = __builtin_bit_cast(unsigned, x);
  u += 0x7fffu + ((u >> 16) & 1u);  // round-to-nearest-even
  return (unsigned short)(u >> 16);
}
__device__ inline unsigned pk_bf16(float a, float b) {
  return (unsigned)bf_bits(a) | ((unsigned)bf_bits(b) << 16);
}

// ---------------- K1a: g1 = relu(s @ Wg1 + bg1)  (8 x 2048) ----------------
__global__ void __launch_bounds__(256) k_gate1(const float* __restrict__ s,
                                               const float* __restrict__ Wg1,
                                               const float* __restrict__ bg1,
                                               float* __restrict__ g1) {
  __shared__ float red[16][16][8];
  int t = threadIdx.x;
  int c = t & 15, kk = t >> 4;
  int h = blockIdx.x * 16 + c;
  float acc[8];
#pragma unroll
  for (int b = 0; b < 8; ++b) acc[b] = 0.f;
  int k0 = kk * 64;
  for (int k = k0; k < k0 + 64; ++k) {
    float w = Wg1[(size_t)k * H1 + h];
#pragma unroll
    for (int b = 0; b < 8; ++b) acc[b] += s[b * EMB + k] * w;
  }
#pragma unroll
  for (int b = 0; b < 8; ++b) red[kk][c][b] = acc[b];
  __syncthreads();
  if (t < 128) {
    int cc = t >> 3, b = t & 7;
    float v = 0.f;
#pragma unroll
    for (int q = 0; q < 16; ++q) v += red[q][cc][b];
    int hh = blockIdx.x * 16 + cc;
    v += bg1[hh];
    g1[b * H1 + hh] = fmaxf(v, 0.f);
  }
}

// ---------------- K1b: logits = g1 @ Wg2 + bg2  (8 x 16) ----------------
__global__ void __launch_bounds__(256) k_gate2(const float* __restrict__ g1,
                                               const float* __restrict__ Wg2,
                                               const float* __restrict__ bg2,
                                               float* __restrict__ logits) {
  __shared__ float red[256][8];
  int e = blockIdx.x, t = threadIdx.x;
  int k0 = t * 8;
  float wv[8];
#pragma unroll
  for (int j = 0; j < 8; ++j) wv[j] = Wg2[(size_t)(k0 + j) * NEXP + e];
  float acc[8];
#pragma unroll
  for (int b = 0; b < 8; ++b) {
    float4 ga = *(const float4*)&g1[b * H1 + k0];
    float4 gb = *(const float4*)&g1[b * H1 + k0 + 4];
    acc[b] = ga.x * wv[0] + ga.y * wv[1] + ga.z * wv[2] + ga.w * wv[3] +
             gb.x * wv[4] + gb.y * wv[5] + gb.z * wv[6] + gb.w * wv[7];
  }
#pragma unroll
  for (int b = 0; b < 8; ++b) red[t][b] = acc[b];
  __syncthreads();
  for (int off = 128; off > 0; off >>= 1) {
    if (t < off) {
#pragma unroll
      for (int b = 0; b < 8; ++b) red[t][b] += red[t + off][b];
    }
    __syncthreads();
  }
  if (t < 8) logits[t * NEXP + e] = red[0][t] + bg2[e];
}

// ---------------- K2: base[e,b,h] = s @ W1s + b1  (16 x 8 x 2048) ----------------
__global__ void __launch_bounds__(512) k_base(const float* __restrict__ s,
                                              const float* __restrict__ W1,
                                              const float* __restrict__ b1,
                                              float* __restrict__ base) {
  __shared__ float sl[8 * EMB];     // 32 KB
  __shared__ float red[8][64][17];  // 34 KB
  int t = threadIdx.x;
  int ht = blockIdx.x;
  int e = blockIdx.y;
#pragma unroll
  for (int i = 0; i < 4; ++i) {
    int idx = (t + i * 512) * 4;
    *(float4*)&sl[idx] = *(const float4*)&s[idx];
  }
  __syncthreads();
  int hp = t & 63;
  int kk = t >> 6;
  int h = ht * 128 + hp * 2;
  const float* wp = W1 + (size_t)e * 1056 * H1 + h;
  float a0[8], a1[8];
#pragma unroll
  for (int b = 0; b < 8; ++b) { a0[b] = 0.f; a1[b] = 0.f; }
  int k0 = kk * 128;
  for (int k = k0; k < k0 + 128; ++k) {
    float2 w = *(const float2*)(wp + (size_t)k * H1);
#pragma unroll
    for (int b = 0; b < 8; ++b) {
      float sv = sl[b * EMB + k];
      a0[b] += sv * w.x;
      a1[b] += sv * w.y;
    }
  }
#pragma unroll
  for (int b = 0; b < 8; ++b) {
    red[kk][hp][b * 2] = a0[b];
    red[kk][hp][b * 2 + 1] = a1[b];
  }
  __syncthreads();
  if (t < 64) {
    int hh = ht * 128 + t * 2;
#pragma unroll
    for (int b = 0; b < 8; ++b) {
      float v0 = 0.f, v1 = 0.f;
#pragma unroll
      for (int q = 0; q < 8; ++q) {
        v0 += red[q][t][b * 2];
        v1 += red[q][t][b * 2 + 1];
      }
      float2 bv = *(const float2*)&b1[e * H1 + hh];
      float2 o;
      o.x = v0 + bv.x;
      o.y = v1 + bv.y;
      *(float2*)&base[(size_t)(e * 8 + b) * H1 + hh] = o;
    }
  }
}

// ---------------- K-pack: dst[n][k] (bf16) = src[k][n] (fp32), batched ----------------
// grid (N/64, K/64, batch), block 256.
__global__ void __launch_bounds__(256) k_packT(const float* __restrict__ src,
                                               unsigned short* __restrict__ dst,
                                               int K, int N, long bstride) {
  __shared__ float tl[64][65];
  const float* S = src + (size_t)blockIdx.z * bstride;
  unsigned short* D = dst + (size_t)blockIdx.z * bstride;
  int nt = blockIdx.x, kt = blockIdx.y, t = threadIdx.x;
  int r = t >> 4, c4 = (t & 15) * 4;
#pragma unroll
  for (int i = 0; i < 4; ++i) {
    int row = r + i * 16;
    float4 v = *(const float4*)&S[(size_t)(kt * 64 + row) * N + nt * 64 + c4];
    *(float4*)&tl[row][c4] = v;
  }
  __syncthreads();
#pragma unroll
  for (int j = 0; j < 2; ++j) {
    int nl = (t >> 3) + j * 32;
    int k8 = (t & 7) * 8;
    union { short8 v; unsigned u[4]; } p;
#pragma unroll
    for (int q = 0; q < 4; ++q)
      p.u[q] = pk_bf16(tl[k8 + 2 * q][nl], tl[k8 + 2 * q + 1][nl]);
    *(short8*)&D[(size_t)(nt * 64 + nl) * K + kt * 64 + k8] = p.v;
  }
}

// ---------------- K-h: h[e][m=c*8+b][k] = relu(base[e,b,k] + W1c[e,c,k]) (bf16) -------
__global__ void __launch_bounds__(256) k_h(const float* __restrict__ base,
                                           const float* __restrict__ W1,
                                           unsigned short* __restrict__ h) {
  int c = blockIdx.x, e = blockIdx.y;
  int t = threadIdx.x;
  int b = t >> 5, l = t & 31;
  const float* bp = base + ((size_t)e * 8 + b) * H1;
  const float* cp = W1 + (size_t)e * 1056 * H1 + (size_t)EMB * H1 + (size_t)c * H1;
  unsigned short* hp = h + ((size_t)e * 256 + c * 8 + b) * H1;
#pragma unroll
  for (int kc = 0; kc < 8; ++kc) {
    int k = kc * 256 + l * 8;
    float4 x0 = *(const float4*)&bp[k];
    float4 x1 = *(const float4*)&bp[k + 4];
    float4 y0 = *(const float4*)&cp[k];
    float4 y1 = *(const float4*)&cp[k + 4];
    union { short8 v; unsigned u[4]; } p;
    p.u[0] = pk_bf16(fmaxf(x0.x + y0.x, 0.f), fmaxf(x0.y + y0.y, 0.f));
    p.u[1] = pk_bf16(fmaxf(x0.z + y0.z, 0.f), fmaxf(x0.w + y0.w, 0.f));
    p.u[2] = pk_bf16(fmaxf(x1.x + y1.x, 0.f), fmaxf(x1.y + y1.y, 0.f));
    p.u[3] = pk_bf16(fmaxf(x1.z + y1.z, 0.f), fmaxf(x1.w + y1.w, 0.f));
    *(short8*)&hp[k] = p.v;
  }
}

// ---------------- K3: eo2[ks][c,e,b,d] partial GEMM  h @ W2T  (pure MFMA) ----------------
// grid (8 dt, 8 = 4 mt x 2 ks, 16 e), block 256, no LDS, no barriers.
__global__ void __launch_bounds__(256) k_egemm(const unsigned short* __restrict__ h,
                                               const unsigned short* __restrict__ W2T,
                                               float* __restrict__ eo2) {
  int dt = blockIdx.x;
  int mk = blockIdx.y;
  int e = blockIdx.z;
  int mt = mk & 3, ks = mk >> 2;
  int t = threadIdx.x, lane = t & 63, w = t >> 6;
  int fr = lane & 15, quad = lane >> 4;
  int n = dt * 64 + w * 16 + fr;
  const unsigned short* hA = h + ((size_t)e * 256 + mt * 64 + fr) * H1 + ks * 1024 + quad * 8;
  const unsigned short* bB = W2T + ((size_t)e * H2 + n) * H1 + ks * 1024 + quad * 8;
  floatx4 zero4 = {0.f, 0.f, 0.f, 0.f};
  floatx4 acc[4];
#pragma unroll
  for (int r = 0; r < 4; ++r) acc[r] = zero4;
#pragma unroll 2
  for (int k0 = 0; k0 < 1024; k0 += 32) {
    short8 bf = *(const short8*)&bB[k0];
#pragma unroll
    for (int rt = 0; rt < 4; ++rt) {
      short8 af = *(const short8*)&hA[(size_t)rt * 16 * H1 + k0];
      acc[rt] = __builtin_amdgcn_mfma_f32_16x16x32_bf16(af, bf, acc[rt], 0, 0, 0);
    }
  }
  float* op = eo2 + (size_t)ks * 2097152;
#pragma unroll
  for (int rt = 0; rt < 4; ++rt) {
#pragma unroll
    for (int i = 0; i < 4; ++i) {
      int gm = mt * 64 + rt * 16 + quad * 4 + i;
      op[(((size_t)(gm >> 3) * NEXP + e) * 8 + (gm & 7)) * H2 + n] = acc[rt][i];
    }
  }
}

// ---------------- K4: z = sum_e softmax(logits)[b,e]*(eo+b2) -> bf16 ----------------
__global__ void __launch_bounds__(256) k_mix(const float* __restrict__ eo2,
                                             const float* __restrict__ logits,
                                             const float* __restrict__ b2,
                                             unsigned short* __restrict__ zbf) {
  int dt = blockIdx.x;  // 8
  int c = blockIdx.y;   // 32
  int t = threadIdx.x;
  int d = dt * 64 + (t & 63);
  int bq = t >> 6;
#pragma unroll
  for (int bi = 0; bi < 2; ++bi) {
    int b = bq + bi * 4;
    float lg[16];
    float mx = -1e30f;
#pragma unroll
    for (int e2 = 0; e2 < 16; ++e2) {
      lg[e2] = logits[b * NEXP + e2];
      mx = fmaxf(mx, lg[e2]);
    }
    float sum = 0.f;
#pragma unroll
    for (int e2 = 0; e2 < 16; ++e2) {
      lg[e2] = __expf(lg[e2] - mx);
      sum += lg[e2];
    }
    float inv = 1.f / sum;
    float acc = 0.f;
#pragma unroll
    for (int e2 = 0; e2 < 16; ++e2) {
      size_t idx = (((size_t)c * NEXP + e2) * 8 + b) * H2 + d;
      float v = eo2[idx] + eo2[idx + 2097152] + b2[e2 * H2 + d];
      acc += lg[e2] * v;
    }
    acc *= inv;
    zbf[((size_t)c * 8 + b) * H2 + d] = bf_bits(acc);
  }
}

// ---------------- K5: out = z_bf16 @ {WAT,WBT}^T + bias  (pure MFMA) ----------------
// grid (256 nt, 2 mt, 2 ms), block 256, no LDS, no barriers.
__global__ void __launch_bounds__(256) k_lora(const unsigned short* __restrict__ zbf,
                                              const unsigned short* __restrict__ WAT,
                                              const float* __restrict__ bA,
                                              const unsigned short* __restrict__ WBT,
                                              const float* __restrict__ bB,
                                              float* __restrict__ out) {
  int nt = blockIdx.x, mt = blockIdx.y, ms = blockIdx.z;
  const unsigned short* WT = ms ? WBT : WAT;
  const float* bias = ms ? bB : bA;
  float* o = out + (size_t)ms * 4194304;
  int t = threadIdx.x, lane = t & 63, w = t >> 6;
  int fr = lane & 15, quad = lane >> 4;
  int n = nt * 64 + w * 16 + fr;
  int m0 = mt * 128;
  const unsigned short* A = zbf + ((size_t)m0 + fr) * H2 + quad * 8;
  const unsigned short* B = WT + (size_t)n * H2 + quad * 8;
  floatx4 zero4 = {0.f, 0.f, 0.f, 0.f};
  floatx4 acc[8];
#pragma unroll
  for (int r = 0; r < 8; ++r) acc[r] = zero4;
#pragma unroll 2
  for (int k0 = 0; k0 < H2; k0 += 32) {
    short8 bf = *(const short8*)&B[k0];
#pragma unroll
    for (int rt = 0; rt < 8; ++rt) {
      short8 af = *(const short8*)&A[(size_t)rt * 16 * H2 + k0];
      acc[rt] = __builtin_amdgcn_mfma_f32_16x16x32_bf16(af, bf, acc[rt], 0, 0, 0);
    }
  }
  float bv = bias[n];
#pragma unroll
  for (int rt = 0; rt < 8; ++rt) {
#pragma unroll
    for (int i = 0; i < 4; ++i) {
      int m = m0 + rt * 16 + quad * 4 + i;
      o[(size_t)m * NBIG + n] = acc[rt][i] + bv;
    }
  }
}

extern "C" void kernel_launch(void* const* d_in, const int* in_sizes, int n_in,
                              void* d_out, int out_size, void* d_ws, size_t ws_size,
                              hipStream_t stream) {
  const float* s = (const float*)d_in[0];
  const float* Wg1 = (const float*)d_in[1];
  const float* bg1 = (const float*)d_in[2];
  const float* Wg2 = (const float*)d_in[3];
  const float* bg2 = (const float*)d_in[4];
  const float* W1 = (const float*)d_in[5];
  const float* b1 = (const float*)d_in[6];
  const float* W2 = (const float*)d_in[7];
  const float* b2 = (const float*)d_in[8];
  const float* WA = (const float*)d_in[9];
  const float* bA = (const float*)d_in[10];
  const float* WB = (const float*)d_in[11];
  const float* bB = (const float*)d_in[12];
  float* out = (float*)d_out;

  char* ws = (char*)d_ws;
  float* g1 = (float*)(ws);                                   // 64 KB
  float* logits = (float*)(ws + 65536);                       // 512 B
  float* base = (float*)(ws + 131072);                        // 1 MB
  unsigned short* h = (unsigned short*)(ws + 1179648);        // 16.78 MB
  float* eo2 = (float*)(ws + 17956864);                       // 16.78 MB (2 parts)
  unsigned short* zbf = (unsigned short*)(ws + 34734080);     // 256 KB
  unsigned short* W2T = (unsigned short*)(ws + 34996224);     // 33.55 MB
  unsigned short* WAT = (unsigned short*)(ws + 68550656);     // 16.78 MB
  unsigned short* WBT = (unsigned short*)(ws + 85327872);     // 16.78 MB

  k_gate1<<<128, 256, 0, stream>>>(s, Wg1, bg1, g1);
  k_gate2<<<16, 256, 0, stream>>>(g1, Wg2, bg2, logits);
  k_packT<<<dim3(8, 32, 16), 256, 0, stream>>>(W2, W2T, H1, H2, (long)H1 * H2);
  k_packT<<<dim3(256, 8, 1), 256, 0, stream>>>(WA, WAT, H2, NBIG, 0);
  k_packT<<<dim3(256, 8, 1), 256, 0, stream>>>(WB, WBT, H2, NBIG, 0);
  k_base<<<dim3(16, 16), 512, 0, stream>>>(s, W1, b1, base);
  k_h<<<dim3(32, 16), 256, 0, stream>>>(base, W1, h);
  k_egemm<<<dim3(8, 8, 16), 256, 0, stream>>>(h, W2T, eo2);
  k_mix<<<dim3(8, 32), 256, 0, stream>>>(eo2, logits, b2, zbf);
  k_lora<<<dim3(256, 2, 2), 256, 0, stream>>>(zbf, WAT, bA, WBT, bB, out);
}

// Round 4
// 398.703 us; speedup vs baseline: 1.2640x; 1.2640x over previous
//
#include <hip/hip_runtime.h>
#include <hip/hip_bf16.h>

#define EMB 1024
#define CTX 32
#define NEXP 16
#define H1 2048
#define H2 512
#define NBIG 16384  // F_IN*R == R*F_OUT

typedef __attribute__((ext_vector_type(8))) short short8;
typedef __attribute__((ext_vector_type(4))) float floatx4;
typedef const __attribute__((address_space(1))) void* gas_t;
typedef __attribute__((address_space(3))) void* las_t;

__device__ __forceinline__ void gl16(const unsigned short* g, unsigned short* l) {
  __builtin_amdgcn_global_load_lds((gas_t)(const void*)g, (las_t)(void*)l, 16, 0, 0);
}

__device__ inline unsigned short bf_bits(float x) {
  unsigned u = __builtin_bit_cast(unsigned, x);
  u += 0x7fffu + ((u >> 16) & 1u);  // round-to-nearest-even
  return (unsigned short)(u >> 16);
}
__device__ inline unsigned pk_bf16(float a, float b) {
  return (unsigned)bf_bits(a) | ((unsigned)bf_bits(b) << 16);
}

// ---------------- K1a: g1 = relu(s @ Wg1 + bg1)  (8 x 2048) ----------------
__global__ void __launch_bounds__(256) k_gate1(const float* __restrict__ s,
                                               const float* __restrict__ Wg1,
                                               const float* __restrict__ bg1,
                                               float* __restrict__ g1) {
  __shared__ float red[16][16][8];
  int t = threadIdx.x;
  int c = t & 15, kk = t >> 4;
  int h = blockIdx.x * 16 + c;
  float acc[8];
#pragma unroll
  for (int b = 0; b < 8; ++b) acc[b] = 0.f;
  int k0 = kk * 64;
  for (int k = k0; k < k0 + 64; ++k) {
    float w = Wg1[(size_t)k * H1 + h];
#pragma unroll
    for (int b = 0; b < 8; ++b) acc[b] += s[b * EMB + k] * w;
  }
#pragma unroll
  for (int b = 0; b < 8; ++b) red[kk][c][b] = acc[b];
  __syncthreads();
  if (t < 128) {
    int cc = t >> 3, b = t & 7;
    float v = 0.f;
#pragma unroll
    for (int q = 0; q < 16; ++q) v += red[q][cc][b];
    int hh = blockIdx.x * 16 + cc;
    v += bg1[hh];
    g1[b * H1 + hh] = fmaxf(v, 0.f);
  }
}

// ---------------- K1b: logits = g1 @ Wg2 + bg2  (8 x 16) ----------------
__global__ void __launch_bounds__(256) k_gate2(const float* __restrict__ g1,
                                               const float* __restrict__ Wg2,
                                               const float* __restrict__ bg2,
                                               float* __restrict__ logits) {
  __shared__ float red[256][8];
  int e = blockIdx.x, t = threadIdx.x;
  int k0 = t * 8;
  float wv[8];
#pragma unroll
  for (int j = 0; j < 8; ++j) wv[j] = Wg2[(size_t)(k0 + j) * NEXP + e];
  float acc[8];
#pragma unroll
  for (int b = 0; b < 8; ++b) {
    float4 ga = *(const float4*)&g1[b * H1 + k0];
    float4 gb = *(const float4*)&g1[b * H1 + k0 + 4];
    acc[b] = ga.x * wv[0] + ga.y * wv[1] + ga.z * wv[2] + ga.w * wv[3] +
             gb.x * wv[4] + gb.y * wv[5] + gb.z * wv[6] + gb.w * wv[7];
  }
#pragma unroll
  for (int b = 0; b < 8; ++b) red[t][b] = acc[b];
  __syncthreads();
  for (int off = 128; off > 0; off >>= 1) {
    if (t < off) {
#pragma unroll
      for (int b = 0; b < 8; ++b) red[t][b] += red[t + off][b];
    }
    __syncthreads();
  }
  if (t < 8) logits[t * NEXP + e] = red[0][t] + bg2[e];
}

// ---------------- K2: base[e,b,h] = s @ W1s + b1 ----------------
__global__ void __launch_bounds__(512) k_base(const float* __restrict__ s,
                                              const float* __restrict__ W1,
                                              const float* __restrict__ b1,
                                              float* __restrict__ base) {
  __shared__ float sl[8 * EMB];
  __shared__ float red[8][64][17];
  int t = threadIdx.x;
  int ht = blockIdx.x;
  int e = blockIdx.y;
#pragma unroll
  for (int i = 0; i < 4; ++i) {
    int idx = (t + i * 512) * 4;
    *(float4*)&sl[idx] = *(const float4*)&s[idx];
  }
  __syncthreads();
  int hp = t & 63;
  int kk = t >> 6;
  int h = ht * 128 + hp * 2;
  const float* wp = W1 + (size_t)e * 1056 * H1 + h;
  float a0[8], a1[8];
#pragma unroll
  for (int b = 0; b < 8; ++b) { a0[b] = 0.f; a1[b] = 0.f; }
  int k0 = kk * 128;
  for (int k = k0; k < k0 + 128; ++k) {
    float2 w = *(const float2*)(wp + (size_t)k * H1);
#pragma unroll
    for (int b = 0; b < 8; ++b) {
      float sv = sl[b * EMB + k];
      a0[b] += sv * w.x;
      a1[b] += sv * w.y;
    }
  }
#pragma unroll
  for (int b = 0; b < 8; ++b) {
    red[kk][hp][b * 2] = a0[b];
    red[kk][hp][b * 2 + 1] = a1[b];
  }
  __syncthreads();
  if (t < 64) {
    int hh = ht * 128 + t * 2;
#pragma unroll
    for (int b = 0; b < 8; ++b) {
      float v0 = 0.f, v1 = 0.f;
#pragma unroll
      for (int q = 0; q < 8; ++q) {
        v0 += red[q][t][b * 2];
        v1 += red[q][t][b * 2 + 1];
      }
      float2 bv = *(const float2*)&b1[e * H1 + hh];
      float2 o;
      o.x = v0 + bv.x;
      o.y = v1 + bv.y;
      *(float2*)&base[(size_t)(e * 8 + b) * H1 + hh] = o;
    }
  }
}

// ---- K-packW: fp32 [K][Nsrc] -> tiled-swizzled bf16 [K/64][Ndst][8c][8] ----
// grid (Nsrc/64, K/64, batch), block 256. Coalesced read + coalesced write.
__global__ void __launch_bounds__(256) k_packW(const float* __restrict__ src,
                                               unsigned short* __restrict__ dst,
                                               int Nsrc, int Ndst, int n_off,
                                               long sbs, long dbs) {
  __shared__ float tl[64][65];
  int nt = blockIdx.x, kb = blockIdx.y, bz = blockIdx.z, t = threadIdx.x;
  const float* S = src + (size_t)bz * sbs + (size_t)kb * 64 * Nsrc + nt * 64;
  int r = t >> 4, c4 = (t & 15) * 4;
#pragma unroll
  for (int i = 0; i < 4; ++i) {
    int row = r + i * 16;
    float4 v = *(const float4*)&S[(size_t)row * Nsrc + c4];
    *(float4*)&tl[row][c4] = v;
  }
  __syncthreads();
  int nl = t >> 2;
  int cb = (t & 3) * 2;
  int key = nl & 7;
  unsigned short* D = dst + (size_t)bz * dbs +
                      ((size_t)kb * Ndst + n_off + nt * 64 + nl) * 64;
#pragma unroll
  for (int j = 0; j < 2; ++j) {
    int cp = cb + j;
    int k0 = (cp ^ key) * 8;
    union { short8 v; unsigned u[4]; } p;
#pragma unroll
    for (int q = 0; q < 4; ++q)
      p.u[q] = pk_bf16(tl[k0 + 2 * q][nl], tl[k0 + 2 * q + 1][nl]);
    *(short8*)&D[cp * 8] = p.v;
  }
}

// ---- K-h: h_t[e][kb][m][8c][8] = relu(base[e,b,:]+W1c[e,c,:]) tiled bf16 ----
__global__ void __launch_bounds__(256) k_h(const float* __restrict__ base,
                                           const float* __restrict__ W1,
                                           unsigned short* __restrict__ h_t) {
  int c = blockIdx.x, e = blockIdx.y;
  int t = threadIdx.x;
  int b = t >> 5, l = t & 31;
  int m = c * 8 + b;
  const float* bp = base + ((size_t)e * 8 + b) * H1;
  const float* cp = W1 + ((size_t)e * 1056 + EMB + c) * H1;
  unsigned short* hp = h_t + (size_t)e * 32 * 256 * 64;
#pragma unroll
  for (int kc = 0; kc < 8; ++kc) {
    int k = kc * 256 + l * 8;
    int kb = k >> 6;
    int cc = (k >> 3) & 7;
    int cpx = cc ^ (b & 7);
    float4 x0 = *(const float4*)&bp[k];
    float4 x1 = *(const float4*)&bp[k + 4];
    float4 y0 = *(const float4*)&cp[k];
    float4 y1 = *(const float4*)&cp[k + 4];
    union { short8 v; unsigned u[4]; } p;
    p.u[0] = pk_bf16(fmaxf(x0.x + y0.x, 0.f), fmaxf(x0.y + y0.y, 0.f));
    p.u[1] = pk_bf16(fmaxf(x0.z + y0.z, 0.f), fmaxf(x0.w + y0.w, 0.f));
    p.u[2] = pk_bf16(fmaxf(x1.x + y1.x, 0.f), fmaxf(x1.y + y1.y, 0.f));
    p.u[3] = pk_bf16(fmaxf(x1.z + y1.z, 0.f), fmaxf(x1.w + y1.w, 0.f));
    *(short8*)&hp[((size_t)kb * 256 + m) * 64 + cpx * 8] = p.v;
  }
}

// ---- K3: eo2[ks][c,e,b,d] = h @ W2 (m97-style: global_load_lds + ds_read_b128) ----
// 512 blocks = e16 x mt4 x nt4 x ks2; BM=64 BN=128 BK=64. LDS 24KB.
__global__ void __launch_bounds__(256) k_egemm(const unsigned short* __restrict__ h_t,
                                               const unsigned short* __restrict__ W2t,
                                               float* __restrict__ eo2) {
  __shared__ __align__(16) unsigned short As[4096];   // 64 rows x 64 (8KB)
  __shared__ __align__(16) unsigned short Bs[8192];   // 128 rows x 64 (16KB)
  int id = blockIdx.x;
  int e = (id & 7) + 8 * ((id >> 3) & 1);   // 2 experts per XCD class
  int r = id >> 4;
  int mt = r & 3, nt = (r >> 2) & 3, ks = (r >> 4) & 1;
  int t = threadIdx.x, lane = t & 63, w = t >> 6;
  int fr = lane & 15, quad = lane >> 4;
  int key = fr & 7;

  const unsigned short* hA = h_t + (size_t)e * 524288 + mt * 4096;
  const unsigned short* wB = W2t + (size_t)e * 1048576 + nt * 8192;

  floatx4 zero4 = {0.f, 0.f, 0.f, 0.f};
  floatx4 acc[4][2];
#pragma unroll
  for (int i = 0; i < 4; ++i) { acc[i][0] = zero4; acc[i][1] = zero4; }

  for (int i = 0; i < 16; ++i) {
    int kb = ks * 16 + i;
    __syncthreads();
    const unsigned short* asrc = hA + (size_t)kb * 16384 + t * 8;
    const unsigned short* bsrc = wB + (size_t)kb * 32768 + t * 8;
    gl16(asrc, &As[t * 8]);
    gl16(asrc + 2048, &As[t * 8 + 2048]);
    gl16(bsrc, &Bs[t * 8]);
    gl16(bsrc + 2048, &Bs[t * 8 + 2048]);
    gl16(bsrc + 4096, &Bs[t * 8 + 4096]);
    gl16(bsrc + 6144, &Bs[t * 8 + 6144]);
    __syncthreads();
#pragma unroll
    for (int ks2 = 0; ks2 < 2; ++ks2) {
      int cof = ((ks2 * 4 + quad) ^ key) * 8;
      short8 bf0 = *(const short8*)&Bs[w * 2048 + fr * 64 + cof];
      short8 bf1 = *(const short8*)&Bs[w * 2048 + 1024 + fr * 64 + cof];
#pragma unroll
      for (int rt = 0; rt < 4; ++rt) {
        short8 af = *(const short8*)&As[rt * 1024 + fr * 64 + cof];
        acc[rt][0] = __builtin_amdgcn_mfma_f32_16x16x32_bf16(af, bf0, acc[rt][0], 0, 0, 0);
        acc[rt][1] = __builtin_amdgcn_mfma_f32_16x16x32_bf16(af, bf1, acc[rt][1], 0, 0, 0);
      }
    }
  }
  float* op = eo2 + (size_t)ks * 2097152;
  int d0 = nt * 128 + w * 32 + fr;
#pragma unroll
  for (int nt2 = 0; nt2 < 2; ++nt2) {
    int d = d0 + nt2 * 16;
#pragma unroll
    for (int rt = 0; rt < 4; ++rt) {
#pragma unroll
      for (int i = 0; i < 4; ++i) {
        int gm = mt * 64 + rt * 16 + quad * 4 + i;
        op[(((size_t)(gm >> 3) * NEXP + e) * 8 + (gm & 7)) * H2 + d] = acc[rt][nt2][i];
      }
    }
  }
}

// ---- K4: z_t tiled bf16 = sum_e softmax * (eo2a+eo2b+b2) ----
// grid (32 c, 2 half), 256 thr, each thread one 8-d chunk per (b).
__global__ void __launch_bounds__(256) k_mix(const float* __restrict__ eo2,
                                             const float* __restrict__ logits,
                                             const float* __restrict__ b2,
                                             unsigned short* __restrict__ z_t) {
  int c = blockIdx.x, half = blockIdx.y, t = threadIdx.x;
  int b = t >> 5;
  int dc = half * 32 + (t & 31);
  int d0 = dc * 8;
  int m = c * 8 + b;
  float lg[16];
  float mx = -1e30f;
#pragma unroll
  for (int e = 0; e < 16; ++e) {
    lg[e] = logits[b * NEXP + e];
    mx = fmaxf(mx, lg[e]);
  }
  float sum = 0.f;
#pragma unroll
  for (int e = 0; e < 16; ++e) {
    lg[e] = __expf(lg[e] - mx);
    sum += lg[e];
  }
  float inv = 1.f / sum;
  float o[8];
#pragma unroll
  for (int j = 0; j < 8; ++j) o[j] = 0.f;
#pragma unroll
  for (int e = 0; e < 16; ++e) {
    float wl = lg[e] * inv;
    const float* p = &eo2[(((size_t)c * NEXP + e) * 8 + b) * H2 + d0];
    float4 x0 = *(const float4*)p;
    float4 x1 = *(const float4*)(p + 4);
    float4 y0 = *(const float4*)(p + 2097152);
    float4 y1 = *(const float4*)(p + 2097152 + 4);
    float4 v0 = *(const float4*)&b2[e * H2 + d0];
    float4 v1 = *(const float4*)&b2[e * H2 + d0 + 4];
    o[0] += wl * (x0.x + y0.x + v0.x);
    o[1] += wl * (x0.y + y0.y + v0.y);
    o[2] += wl * (x0.z + y0.z + v0.z);
    o[3] += wl * (x0.w + y0.w + v0.w);
    o[4] += wl * (x1.x + y1.x + v1.x);
    o[5] += wl * (x1.y + y1.y + v1.y);
    o[6] += wl * (x1.z + y1.z + v1.z);
    o[7] += wl * (x1.w + y1.w + v1.w);
  }
  union { short8 v; unsigned u[4]; } p;
#pragma unroll
  for (int q = 0; q < 4; ++q) p.u[q] = pk_bf16(o[2 * q], o[2 * q + 1]);
  int kb = dc >> 3;
  int cpx = (dc & 7) ^ (b & 7);
  *(short8*)&z_t[((size_t)kb * 256 + m) * 64 + cpx * 8] = p.v;
}

// ---- K5: out = z @ [WA|WB] + bias  (m97-style). 512 blocks = nt256 x mt2 ----
// BM=128 BN=128 BK=64, K=512. LDS 32KB.
__global__ void __launch_bounds__(256) k_lora(const unsigned short* __restrict__ z_t,
                                              const unsigned short* __restrict__ Wab_t,
                                              const float* __restrict__ bA,
                                              const float* __restrict__ bB,
                                              float* __restrict__ out) {
  __shared__ __align__(16) unsigned short As[8192];   // 128 x 64 (16KB)
  __shared__ __align__(16) unsigned short Bs[8192];   // 128 x 64 (16KB)
  int id = blockIdx.x;
  int nt = id & 255, mt = id >> 8;
  int t = threadIdx.x, lane = t & 63, w = t >> 6;
  int fr = lane & 15, quad = lane >> 4;
  int key = fr & 7;

  const unsigned short* zA = z_t + mt * 8192;
  const unsigned short* wB = Wab_t + (size_t)nt * 8192;

  floatx4 zero4 = {0.f, 0.f, 0.f, 0.f};
  floatx4 acc[8][2];
#pragma unroll
  for (int i = 0; i < 8; ++i) { acc[i][0] = zero4; acc[i][1] = zero4; }

  for (int kb = 0; kb < 8; ++kb) {
    __syncthreads();
    const unsigned short* asrc = zA + (size_t)kb * 16384 + t * 8;
    const unsigned short* bsrc = wB + (size_t)kb * 2097152 + t * 8;
    gl16(asrc, &As[t * 8]);
    gl16(asrc + 2048, &As[t * 8 + 2048]);
    gl16(asrc + 4096, &As[t * 8 + 4096]);
    gl16(asrc + 6144, &As[t * 8 + 6144]);
    gl16(bsrc, &Bs[t * 8]);
    gl16(bsrc + 2048, &Bs[t * 8 + 2048]);
    gl16(bsrc + 4096, &Bs[t * 8 + 4096]);
    gl16(bsrc + 6144, &Bs[t * 8 + 6144]);
    __syncthreads();
#pragma unroll
    for (int ks2 = 0; ks2 < 2; ++ks2) {
      int cof = ((ks2 * 4 + quad) ^ key) * 8;
      short8 bf0 = *(const short8*)&Bs[w * 2048 + fr * 64 + cof];
      short8 bf1 = *(const short8*)&Bs[w * 2048 + 1024 + fr * 64 + cof];
#pragma unroll
      for (int rt = 0; rt < 8; ++rt) {
        short8 af = *(const short8*)&As[rt * 1024 + fr * 64 + cof];
        acc[rt][0] = __builtin_amdgcn_mfma_f32_16x16x32_bf16(af, bf0, acc[rt][0], 0, 0, 0);
        acc[rt][1] = __builtin_amdgcn_mfma_f32_16x16x32_bf16(af, bf1, acc[rt][1], 0, 0, 0);
      }
    }
  }
  int nb0 = nt * 128 + w * 32 + fr;
#pragma unroll
  for (int nt2 = 0; nt2 < 2; ++nt2) {
    int n = nb0 + nt2 * 16;
    int ms = n >> 14;
    int nn = n & (NBIG - 1);
    float bv = ms ? bB[nn] : bA[nn];
    float* o = out + (size_t)ms * 4194304 + nn;
#pragma unroll
    for (int rt = 0; rt < 8; ++rt) {
#pragma unroll
      for (int i = 0; i < 4; ++i) {
        int m = mt * 128 + rt * 16 + quad * 4 + i;
        o[(size_t)m * NBIG] = acc[rt][nt2][i] + bv;
      }
    }
  }
}

extern "C" void kernel_launch(void* const* d_in, const int* in_sizes, int n_in,
                              void* d_out, int out_size, void* d_ws, size_t ws_size,
                              hipStream_t stream) {
  const float* s = (const float*)d_in[0];
  const float* Wg1 = (const float*)d_in[1];
  const float* bg1 = (const float*)d_in[2];
  const float* Wg2 = (const float*)d_in[3];
  const float* bg2 = (const float*)d_in[4];
  const float* W1 = (const float*)d_in[5];
  const float* b1 = (const float*)d_in[6];
  const float* W2 = (const float*)d_in[7];
  const float* b2 = (const float*)d_in[8];
  const float* WA = (const float*)d_in[9];
  const float* bA = (const float*)d_in[10];
  const float* WB = (const float*)d_in[11];
  const float* bB = (const float*)d_in[12];
  float* out = (float*)d_out;

  char* ws = (char*)d_ws;
  float* g1 = (float*)(ws);                                 // 64 KB
  float* logits = (float*)(ws + 65536);                     // 512 B
  float* base = (float*)(ws + 131072);                      // 1 MB -> ends 1179648
  unsigned short* h_t = (unsigned short*)(ws + 1179648);    // 16.78 MB -> 17956864
  float* eo2 = (float*)(ws + 17956864);                     // 16.78 MB -> 34734080
  unsigned short* z_t = (unsigned short*)(ws + 34734080);   // 256 KB -> 34996224
  unsigned short* W2t = (unsigned short*)(ws + 34996224);   // 33.55 MB -> 68550656
  unsigned short* Wab_t = (unsigned short*)(ws + 68550656); // 33.55 MB -> 102105088

  k_gate1<<<128, 256, 0, stream>>>(s, Wg1, bg1, g1);
  k_gate2<<<16, 256, 0, stream>>>(g1, Wg2, bg2, logits);
  k_base<<<dim3(16, 16), 512, 0, stream>>>(s, W1, b1, base);
  k_h<<<dim3(32, 16), 256, 0, stream>>>(base, W1, h_t);
  k_packW<<<dim3(8, 32, 16), 256, 0, stream>>>(W2, W2t, H2, H2, 0,
                                               (long)H1 * H2, (long)H1 * H2);
  k_packW<<<dim3(256, 8, 1), 256, 0, stream>>>(WA, Wab_t, NBIG, 2 * NBIG, 0, 0, 0);
  k_packW<<<dim3(256, 8, 1), 256, 0, stream>>>(WB, Wab_t, NBIG, 2 * NBIG, NBIG, 0, 0);
  k_egemm<<<512, 256, 0, stream>>>(h_t, W2t, eo2);
  k_mix<<<dim3(32, 2), 256, 0, stream>>>(eo2, logits, b2, z_t);
  k_lora<<<512, 256, 0, stream>>>(z_t, Wab_t, bA, bB, out);
}